// Round 11
// baseline (1479.273 us; speedup 1.0000x reference)
//
#include <hip/hip_runtime.h>
#include <stdint.h>

// GraphSAGE fused layer, MI355X (gfx950). All tensors fp32.
// N=16384, D=64. adj = binary fp32 mask (1.074 GB) -> stream once.
//
// R15: DIAGNOSTIC (Delta-method). R14 falsified the last structural theory
// (branch-free unconditional-store scan still ~3.3 TB/s). Only fit left for
// ALL data incl. R11's 6-pass probe (951us): TLB/translation-cold reads run
// at half rate (miss occupies tracking slot for walk+data => 3.4 = 6.8/2);
// warm reads run full rate; harness's 4.3GB fills re-thrash translation every
// iteration so every scan is cold. Test: R8 fused (unchanged, provides the
// output) THEN a single-pass probe over adj -- it runs translation-WARM
// (sage just touched all pages). dur ~ 1290.6 + warm-read-time:
//   ~1460-1500 -> warm fast, TLB model confirmed -> pre-touch design next.
//   ~1580-1630 -> reads always 3.4 -> R8 is at the read floor -> ROOFLINE.

#define NROWS   16384
#define DDIM    64
#define MAXNNZ  256
#define NBLOCKS 4096

#define PROBE_BLOCKS  2048
#define PROBE_TPB     256
#define PROBE_THREADS ((size_t)PROBE_BLOCKS * PROBE_TPB)    // 524,288
#define ADJ_VECS      ((size_t)NROWS * NROWS / 4)           // 67,108,864

typedef uint32_t u32x4 __attribute__((ext_vector_type(4)));

__device__ uint32_t g_sink[PROBE_THREADS];   // 2 MB, coarse, BSS

__device__ __forceinline__ int lane_rank(unsigned long long m) {
    return __builtin_amdgcn_mbcnt_hi((uint32_t)(m >> 32),
           __builtin_amdgcn_mbcnt_lo((uint32_t)m, 0));
}

// ---------------------------------------------------------------------------
// Single-pass NT read probe over adj (R11's read_probe, passes=1, BSS sink).
// ---------------------------------------------------------------------------
__global__ __launch_bounds__(PROBE_TPB, 4) void read_probe(
    const uint32_t* __restrict__ src, size_t nvec, int passes)
{
    const u32x4* p = reinterpret_cast<const u32x4*>(src);
    const size_t stride = PROBE_THREADS;
    uint32_t acc = 0;
    for (int ps = 0; ps < passes; ++ps) {
        for (size_t i = (size_t)blockIdx.x * PROBE_TPB + threadIdx.x;
             i + 3 * stride < nvec; i += 4 * stride) {
            const u32x4 v0 = __builtin_nontemporal_load(&p[i]);
            const u32x4 v1 = __builtin_nontemporal_load(&p[i + stride]);
            const u32x4 v2 = __builtin_nontemporal_load(&p[i + 2 * stride]);
            const u32x4 v3 = __builtin_nontemporal_load(&p[i + 3 * stride]);
            acc |= (v0.x | v0.y | v0.z | v0.w);
            acc |= (v1.x | v1.y | v1.z | v1.w);
            acc |= (v2.x | v2.y | v2.z | v2.w);
            acc |= (v3.x | v3.y | v3.z | v3.w);
        }
    }
    g_sink[(size_t)blockIdx.x * PROBE_TPB + threadIdx.x] = acc;
}

// ---------------------------------------------------------------------------
// Best-known fused kernel (R8, 1290.6 us). Unchanged; produces the output.
// ---------------------------------------------------------------------------
__global__ __launch_bounds__(256, 4) void sage_fused(
    const float* __restrict__ X,     // (N, 64)
    const float* __restrict__ adj,   // (N, N)
    const float* __restrict__ W,     // (128, 64) row-major, L2-hot (32 KB)
    const float* __restrict__ bias,  // (64,)
    float* __restrict__ out)         // (N, 64)
{
    __shared__ int   slist[4][MAXNNZ];
    __shared__ float scat[4][2 * DDIM];

    const int tid  = threadIdx.x;
    const int lane = tid & 63;
    const int w    = tid >> 6;
    const int row  = blockIdx.x * 4 + w;

    const float bv = bias[lane];

    const int start = (row * 7 + (row >> 4)) & 15;
    const u32x4* rowp = reinterpret_cast<const u32x4*>(adj + (size_t)row * NROWS);

    u32x4 buf[2][4];
    {
        const int ss0 = start;
        const int ss1 = (start + 1) & 15;
#pragma unroll
        for (int q = 0; q < 4; ++q)
            buf[0][q] = __builtin_nontemporal_load(&rowp[ss0 * 256 + q * 64 + lane]);
#pragma unroll
        for (int q = 0; q < 4; ++q)
            buf[1][q] = __builtin_nontemporal_load(&rowp[ss1 * 256 + q * 64 + lane]);
    }

    int cnt = 0;

#pragma unroll 2
    for (int s = 0; s < 16; ++s) {
        const int cur = s & 1;
        const int ss  = (s + start) & 15;

        u32x4 t[4];
#pragma unroll
        for (int q = 0; q < 4; ++q) t[q] = buf[cur][q];

        if (s < 14) {
            const int ssn = (s + 2 + start) & 15;
#pragma unroll
            for (int q = 0; q < 4; ++q)
                buf[cur][q] = __builtin_nontemporal_load(&rowp[ssn * 256 + q * 64 + lane]);
        }

#pragma unroll
        for (int q = 0; q < 4; ++q) {
            const u32x4 vv = t[q];
            const int base = (ss * 256 + q * 64 + lane) * 4;
            const uint32_t w4[4] = { vv.x, vv.y, vv.z, vv.w };
#pragma unroll
            for (int j = 0; j < 4; ++j) {
                const bool nz = (w4[j] != 0);
                const unsigned long long m = __ballot(nz);
                const int p = cnt + lane_rank(m);
                if (nz && p < MAXNNZ) slist[w][p] = base + j;
                cnt += (int)__popcll(m);
            }
        }
    }
    __builtin_amdgcn_wave_barrier();

    const int nnz = cnt;
    const int cn  = (nnz < MAXNNZ) ? nnz : MAXNNZ;

    float acc = 0.0f;
    int k = 0;
    for (; k + 4 <= cn; k += 4) {
        const int j0 = slist[w][k], j1 = slist[w][k + 1];
        const int j2 = slist[w][k + 2], j3 = slist[w][k + 3];
        const float a0 = X[(size_t)j0 * DDIM + lane];
        const float a1 = X[(size_t)j1 * DDIM + lane];
        const float a2 = X[(size_t)j2 * DDIM + lane];
        const float a3 = X[(size_t)j3 * DDIM + lane];
        acc += (a0 + a1) + (a2 + a3);
    }
    for (; k < cn; ++k) acc += X[(size_t)slist[w][k] * DDIM + lane];

    const float xi = X[(size_t)row * DDIM + lane];
    const float h  = (acc + xi) / ((float)nnz + 1.0f);
    scat[w][lane]        = xi;
    scat[w][DDIM + lane] = h;
    __builtin_amdgcn_wave_barrier();

    float z0 = bv, z1 = 0.0f, z2 = 0.0f, z3 = 0.0f;
#pragma unroll 8
    for (int kk = 0; kk < 2 * DDIM; kk += 4) {
        z0 = fmaf(scat[w][kk + 0], W[(kk + 0) * DDIM + lane], z0);
        z1 = fmaf(scat[w][kk + 1], W[(kk + 1) * DDIM + lane], z1);
        z2 = fmaf(scat[w][kk + 2], W[(kk + 2) * DDIM + lane], z2);
        z3 = fmaf(scat[w][kk + 3], W[(kk + 3) * DDIM + lane], z3);
    }
    float z = (z0 + z1) + (z2 + z3);
    z = fmaxf(z, 0.0f);

    float s2 = z * z;
#pragma unroll
    for (int off = 32; off >= 1; off >>= 1) s2 += __shfl_xor(s2, off);
    const float inv = 1.0f / fmaxf(sqrtf(s2), 1e-12f);
    out[(size_t)row * DDIM + lane] = z * inv;
}

// ---------------------------------------------------------------------------
extern "C" void kernel_launch(void* const* d_in, const int* in_sizes, int n_in,
                              void* d_out, int out_size, void* d_ws, size_t ws_size,
                              hipStream_t stream) {
    const float* X   = (const float*)d_in[0];
    const float* adj = (const float*)d_in[1];
    const float* W   = (const float*)d_in[2];
    const float* b   = (const float*)d_in[3];
    float* out = (float*)d_out;

    // Real kernel first (runs translation-cold, as in every prior round).
    sage_fused<<<NBLOCKS, 256, 0, stream>>>(X, adj, W, b, out);

    // Then the single-pass probe: adj pages just touched -> measures the
    // translation-WARM pure-read rate via dur_us delta vs the 1290.6 baseline.
    read_probe<<<PROBE_BLOCKS, PROBE_TPB, 0, stream>>>(
        (const uint32_t*)adj, ADJ_VECS, 1);
}

// Round 12
// 1294.748 us; speedup vs baseline: 1.1425x; 1.1425x over previous
//
#include <hip/hip_runtime.h>
#include <stdint.h>

// GraphSAGE fused layer, MI355X (gfx950). All tensors fp32.
// N=16384, D=64. adj = binary fp32 mask (1.074 GB) -> stream once.
//
// R16: R15 CONFIRMED the TLB model: identical probe loop over adj reads at
// 3.4 TB/s translation-cold (start of iteration, after the harness's 4.3 GB
// fills thrash the per-XCD UTCL2) and 5.69 TB/s translation-warm (right
// after sage touched the pages). Walk-excess arithmetic fits 512 x 2MB pages
// at ~300ns/walk serialized per-XCD. Exploit: overlap walks with streaming.
// Each wave issues ONE 1-dword pre-touch of page (row & 511) at kernel start
// (rows dispatch ~in order -> first ~128 blocks/XCD queue all 512 walks in
// the first microseconds; the walker runs ahead of the stream). The value is
// kept alive by an empty asm at kernel end (rule #17; waitcnt long drained).
// Everything else is R8 verbatim (best verified: 1290.6 us).

#define NROWS   16384
#define DDIM    64
#define MAXNNZ  256       // deg ~ Binom(16384, 32/16384): mean 32, sigma 5.7
#define NBLOCKS 4096

typedef uint32_t u32x4 __attribute__((ext_vector_type(4)));

__device__ __forceinline__ int lane_rank(unsigned long long m) {
    return __builtin_amdgcn_mbcnt_hi((uint32_t)(m >> 32),
           __builtin_amdgcn_mbcnt_lo((uint32_t)m, 0));
}

__global__ __launch_bounds__(256, 4) void sage_fused(
    const float* __restrict__ X,     // (N, 64)
    const float* __restrict__ adj,   // (N, N)
    const float* __restrict__ W,     // (128, 64) row-major, L2-hot (32 KB)
    const float* __restrict__ bias,  // (64,)
    float* __restrict__ out)         // (N, 64)
{
    __shared__ int   slist[4][MAXNNZ];   // per-wave nonzero column list
    __shared__ float scat[4][2 * DDIM];  // per-wave [x_i | h_neigh]

    const int tid  = threadIdx.x;
    const int lane = tid & 63;
    const int w    = tid >> 6;
    const int row  = blockIdx.x * 4 + w;     // one wave per row

    // ---- TLB pre-touch: 1 dword from 2MB-page (row & 511), lane 0 only.
    // Issued FIRST so the per-XCD page-walker runs ahead of the stream.
    uint32_t ptv = 0;
    if (lane == 0) {
        const uint32_t* pt = reinterpret_cast<const uint32_t*>(adj)
                           + ((size_t)(row & 511) << 19);   // 2MB = 2^19 floats
        ptv = __builtin_nontemporal_load(pt);
    }

    const float bv = bias[lane];

    // ---- Scan the 64 KB adj row: 16 stages x (4 x 16B/lane), depth-2 pipeline.
    const int start = (row * 7 + (row >> 4)) & 15;
    const u32x4* rowp = reinterpret_cast<const u32x4*>(adj + (size_t)row * NROWS);

    u32x4 buf[2][4];
    {
        const int ss0 = start;                 // stage 0
        const int ss1 = (start + 1) & 15;      // stage 1
#pragma unroll
        for (int q = 0; q < 4; ++q)
            buf[0][q] = __builtin_nontemporal_load(&rowp[ss0 * 256 + q * 64 + lane]);
#pragma unroll
        for (int q = 0; q < 4; ++q)
            buf[1][q] = __builtin_nontemporal_load(&rowp[ss1 * 256 + q * 64 + lane]);
    }

    int cnt = 0;   // wave-uniform running nonzero count

#pragma unroll 2
    for (int s = 0; s < 16; ++s) {
        const int cur = s & 1;
        const int ss  = (s + start) & 15;      // stage being processed

        u32x4 t[4];
#pragma unroll
        for (int q = 0; q < 4; ++q) t[q] = buf[cur][q];

        if (s < 14) {
            const int ssn = (s + 2 + start) & 15;
#pragma unroll
            for (int q = 0; q < 4; ++q)
                buf[cur][q] = __builtin_nontemporal_load(&rowp[ssn * 256 + q * 64 + lane]);
        }

        // Branchless nonzero extraction: ballot + mbcnt rank + predicated write.
#pragma unroll
        for (int q = 0; q < 4; ++q) {
            const u32x4 vv = t[q];
            const int base = (ss * 256 + q * 64 + lane) * 4;
            const uint32_t w4[4] = { vv.x, vv.y, vv.z, vv.w };
#pragma unroll
            for (int j = 0; j < 4; ++j) {
                const bool nz = (w4[j] != 0);
                const unsigned long long m = __ballot(nz);
                const int p = cnt + lane_rank(m);
                if (nz && p < MAXNNZ) slist[w][p] = base + j;  // predicated store
                cnt += (int)__popcll(m);                       // uniform update
            }
        }
    }
    __builtin_amdgcn_wave_barrier();

    const int nnz = cnt;
    const int cn  = (nnz < MAXNNZ) ? nnz : MAXNNZ;

    // ---- Gather-accumulate neighbor X rows (256 B coalesced reads, cache-hot).
    float acc = 0.0f;
    int k = 0;
    for (; k + 4 <= cn; k += 4) {
        const int j0 = slist[w][k], j1 = slist[w][k + 1];
        const int j2 = slist[w][k + 2], j3 = slist[w][k + 3];
        const float a0 = X[(size_t)j0 * DDIM + lane];
        const float a1 = X[(size_t)j1 * DDIM + lane];
        const float a2 = X[(size_t)j2 * DDIM + lane];
        const float a3 = X[(size_t)j3 * DDIM + lane];
        acc += (a0 + a1) + (a2 + a3);
    }
    for (; k < cn; ++k) acc += X[(size_t)slist[w][k] * DDIM + lane];

    const float xi = X[(size_t)row * DDIM + lane];
    const float h  = (acc + xi) / ((float)nnz + 1.0f);   // deg = rowsum+1 >= 1
    scat[w][lane]        = xi;
    scat[w][DDIM + lane] = h;
    __builtin_amdgcn_wave_barrier();

    // ---- GEMV: z[d] = b[d] + sum_k cat[k] * W[k][d]; W is L1/L2-hot.
    float z0 = bv, z1 = 0.0f, z2 = 0.0f, z3 = 0.0f;
#pragma unroll 8
    for (int kk = 0; kk < 2 * DDIM; kk += 4) {
        z0 = fmaf(scat[w][kk + 0], W[(kk + 0) * DDIM + lane], z0);
        z1 = fmaf(scat[w][kk + 1], W[(kk + 1) * DDIM + lane], z1);
        z2 = fmaf(scat[w][kk + 2], W[(kk + 2) * DDIM + lane], z2);
        z3 = fmaf(scat[w][kk + 3], W[(kk + 3) * DDIM + lane], z3);
    }
    float z = (z0 + z1) + (z2 + z3);
    z = fmaxf(z, 0.0f);

    // ---- Row L2-norm over the 64 lanes, normalize, store.
    float s2 = z * z;
#pragma unroll
    for (int off = 32; off >= 1; off >>= 1) s2 += __shfl_xor(s2, off);
    const float inv = 1.0f / fmaxf(sqrtf(s2), 1e-12f);
    out[(size_t)row * DDIM + lane] = z * inv;

    // ---- Keep the pre-touch load alive (no-op; waitcnt drained long ago).
    asm volatile("" :: "v"(ptv));
}

extern "C" void kernel_launch(void* const* d_in, const int* in_sizes, int n_in,
                              void* d_out, int out_size, void* d_ws, size_t ws_size,
                              hipStream_t stream) {
    const float* X   = (const float*)d_in[0];
    const float* adj = (const float*)d_in[1];
    const float* W   = (const float*)d_in[2];
    const float* b   = (const float*)d_in[3];
    float* out = (float*)d_out;
    sage_fused<<<NBLOCKS, 256, 0, stream>>>(X, adj, W, b, out);
}